// Round 15
// baseline (573.715 us; speedup 1.0000x reference)
//
#include <hip/hip_runtime.h>
#include <math.h>

#define N_NODES 50000
#define N_EDGES 600000
#define N_GRAPHS 512
#define HID 128
#define LAT 64
#define NL 4
#define SSTR 16        // stats padding: 1 float per 64B cache line
#define SSET 4096      // floats per stat set: 256 entries * 16
#define N_TILES 3125   // 16-row tiles, exact
#define TLD 72         // per-wave LDS C half-tile row stride (ushort), 64+8 pad

typedef __attribute__((ext_vector_type(8))) __bf16 bf16x8;
typedef __attribute__((ext_vector_type(4))) float f32x4;

union Chunk {
    bf16x8 v;
    uint4 u4;
    ushort us[8];
};

__device__ __forceinline__ float gelu_exact(float x) {
    return 0.5f * x * (1.0f + erff(x * 0.70710678118654752f));
}
// Branchless gelu via A&S 7.1.26 erf poly (|err| <= 1.5e-7) + fast exp/rcp.
__device__ __forceinline__ float gelu_fast(float x) {
    float ax = fabsf(x) * 0.70710678118654752f;
    float t = __builtin_amdgcn_rcpf(fmaf(0.3275911f, ax, 1.0f));
    float p = t * (0.254829592f +
              t * (-0.284496736f +
              t * (1.421413741f +
              t * (-1.453152027f + t * 1.061405429f))));
    float e = __expf(-ax * ax);
    float erfv = 1.0f - p * e;
    float erfs = copysignf(erfv, x);
    return 0.5f * x * (1.0f + erfs);
}
__device__ __forceinline__ float bf2f(ushort h) {
    return __uint_as_float(((unsigned int)h) << 16);
}
__device__ __forceinline__ ushort f2bf(float f) {  // RNE
    unsigned int u = __float_as_uint(f);
    unsigned int r = (u + 0x7FFFu + ((u >> 16) & 1u)) >> 16;
    return (ushort)r;
}
// float atomic max via sign trick (init to -inf)
__device__ __forceinline__ void atomicMaxF(float* addr, float v) {
    if (v >= 0.f) atomicMax((int*)addr, __float_as_int(v));
    else atomicMin((unsigned int*)addr, __float_as_uint(v));
}

// Canonical row partition p (0..255) -> sub-chunk j (0..7) -> [s0, s1)
__device__ __forceinline__ void sub_range(int p, int j, int& s0, int& s1) {
    int r0 = (p * N_NODES) >> 8;
    int r1 = ((p + 1) * N_NODES) >> 8;
    int len = r1 - r0;
    s0 = r0 + ((len * j) >> 3);
    s1 = r0 + ((len * (j + 1)) >> 3);
}

// ---------------------------------------------------------------------------
// Weight pre-transpose + bf16: Wt[g][n][k] = W_g[k][n], g=0..3 fc1, 4..7 fc2
// ---------------------------------------------------------------------------
__global__ __launch_bounds__(256) void wt_build(const float* __restrict__ fc1w,
                                                const float* __restrict__ fc2w,
                                                ushort* __restrict__ Wt) {
    int i = blockIdx.x * 256 + threadIdx.x;  // 131072
    if (i >= 8 * HID * HID) return;
    int g = i >> 14;
    int rem = i & 16383;
    int n = rem >> 7, k = rem & 127;
    const float* W = (g < 4) ? (fc1w + (long)g * HID * HID) : (fc2w + (long)(g - 4) * HID * HID);
    Wt[i] = f2bf(W[k * HID + n]);
}

// ---------------------------------------------------------------------------
// Column stats over fp32 X -> padded stats
// ---------------------------------------------------------------------------
__global__ __launch_bounds__(256) void col_stats(const float* __restrict__ X,
                                                 float* __restrict__ stats) {
    __shared__ float sh[2048];
    int t = threadIdx.x;
    int tx = t & 31, ty = t >> 5;
    float s[4] = {0, 0, 0, 0}, q[4] = {0, 0, 0, 0};
    const int nTiles = (N_NODES + 63) / 64;  // 782
    for (int tile = blockIdx.x; tile < nTiles; tile += gridDim.x) {
        int r0 = tile * 64;
#pragma unroll
        for (int i = 0; i < 8; ++i) {
            int r = r0 + ty + 8 * i;
            int rc = min(r, N_NODES - 1);
            float4 v = *(const float4*)(X + (long)rc * HID + 4 * tx);
            float w = (r < N_NODES) ? 1.f : 0.f;
            float x0 = v.x * w, x1 = v.y * w, x2 = v.z * w, x3 = v.w * w;
            s[0] += x0; s[1] += x1; s[2] += x2; s[3] += x3;
            q[0] += x0 * v.x; q[1] += x1 * v.y; q[2] += x2 * v.z; q[3] += x3 * v.w;
        }
    }
#pragma unroll
    for (int c = 0; c < 4; ++c) {
        sh[ty * HID + 4 * tx + c] = s[c];
        sh[1024 + ty * HID + 4 * tx + c] = q[c];
    }
    __syncthreads();
    if (ty == 0) {
#pragma unroll
        for (int c = 0; c < 4; ++c) {
            float a = 0, b = 0;
#pragma unroll
            for (int j = 0; j < 8; ++j) {
                a += sh[j * HID + 4 * tx + c];
                b += sh[1024 + j * HID + 4 * tx + c];
            }
            atomicAdd(stats + (4 * tx + c) * SSTR, a);
            atomicAdd(stats + (HID + 4 * tx + c) * SSTR, b);
        }
    }
}

// ---------------------------------------------------------------------------
// BN apply, fp32 in -> bf16 out (input BN). Grid 2048.
// ---------------------------------------------------------------------------
__global__ __launch_bounds__(256) void bn_apply_f32(const float* __restrict__ X,
                                                    ushort* __restrict__ Y,
                                                    const float* __restrict__ stats,
                                                    const float* __restrict__ g,
                                                    const float* __restrict__ b) {
    __shared__ float scL[HID], sfL[HID];
    int t = threadIdx.x;
    if (t < HID) {
        const float invN = 1.0f / (float)N_NODES;
        float mean = stats[t * SSTR] * invN;
        float var = stats[(HID + t) * SSTR] * invN - mean * mean;
        float s = g[t] * rsqrtf(var + 1e-5f);
        scL[t] = s;
        sfL[t] = b[t] - mean * s;
    }
    __syncthreads();
    int c4 = (t & 31) * 4;
    float sc[4], sf[4];
#pragma unroll
    for (int j = 0; j < 4; ++j) { sc[j] = scL[c4 + j]; sf[j] = sfL[c4 + j]; }
    int s0, s1;
    sub_range(blockIdx.x & 255, blockIdx.x >> 8, s0, s1);
    int c0 = s0 * 32, c1 = s1 * 32;
    for (int i = c0 + t; i < c1; i += 256) {
        float4 v = ((const float4*)X)[i];
        ushort4 w;
        w.x = f2bf(v.x * sc[0] + sf[0]);
        w.y = f2bf(v.y * sc[1] + sf[1]);
        w.z = f2bf(v.z * sc[2] + sf[2]);
        w.w = f2bf(v.w * sc[3] + sf[3]);
        ((ushort4*)Y)[i] = w;
    }
}

// BN + gelu, bf16 in -> bf16 out. Grid 2048.
__global__ __launch_bounds__(256) void bn_apply_bf(const ushort* __restrict__ X,
                                                   ushort* __restrict__ Y,
                                                   const float* __restrict__ stats,
                                                   const float* __restrict__ g,
                                                   const float* __restrict__ b) {
    __shared__ float scL[HID], sfL[HID];
    int t = threadIdx.x;
    if (t < HID) {
        const float invN = 1.0f / (float)N_NODES;
        float mean = stats[t * SSTR] * invN;
        float var = stats[(HID + t) * SSTR] * invN - mean * mean;
        float s = g[t] * rsqrtf(var + 1e-5f);
        scL[t] = s;
        sfL[t] = b[t] - mean * s;
    }
    __syncthreads();
    int c8 = (t & 15) * 8;
    float sc[8], sf[8];
#pragma unroll
    for (int j = 0; j < 8; ++j) { sc[j] = scL[c8 + j]; sf[j] = sfL[c8 + j]; }
    int s0, s1;
    sub_range(blockIdx.x & 255, blockIdx.x >> 8, s0, s1);
    int c0 = s0 * 16, c1 = s1 * 16;
    for (int i = c0 + t; i < c1; i += 256) {
        Chunk ch;
        ch.u4 = ((const uint4*)X)[i];
#pragma unroll
        for (int j = 0; j < 8; ++j) {
            float f = bf2f(ch.us[j]) * sc[j] + sf[j];
            ch.us[j] = f2bf(gelu_fast(f));
        }
        ((uint4*)Y)[i] = ch.u4;
    }
}

// ---------------------------------------------------------------------------
// CSR build: counting sort of edges by dst
// ---------------------------------------------------------------------------
__global__ __launch_bounds__(256) void csr_count(const int* __restrict__ dst,
                                                 int* __restrict__ counts) {
    int e = blockIdx.x * blockDim.x + threadIdx.x;
    if (e >= N_EDGES) return;
    atomicAdd(counts + dst[e], 1);
}

__global__ __launch_bounds__(256) void scan_pass1(const int* __restrict__ counts,
                                                  int* __restrict__ offs,
                                                  int* __restrict__ bsum) {
    __shared__ int sh[256];
    int t = threadIdx.x;
    int i = blockIdx.x * 256 + t;
    int v = (i < N_NODES) ? counts[i] : 0;
    sh[t] = v;
    __syncthreads();
    for (int off = 1; off < 256; off <<= 1) {
        int a = (t >= off) ? sh[t - off] : 0;
        __syncthreads();
        sh[t] += a;
        __syncthreads();
    }
    if (i < N_NODES) offs[i] = sh[t] - v;
    if (t == 255) bsum[blockIdx.x] = sh[255];
}

__global__ __launch_bounds__(256) void scan_pass2(int* __restrict__ bsum, int nblk) {
    __shared__ int sh[256];
    int t = threadIdx.x;
    int v = (t < nblk) ? bsum[t] : 0;
    sh[t] = v;
    __syncthreads();
    for (int off = 1; off < 256; off <<= 1) {
        int a = (t >= off) ? sh[t - off] : 0;
        __syncthreads();
        sh[t] += a;
        __syncthreads();
    }
    if (t < nblk) bsum[t] = sh[t] - v;
}

__global__ __launch_bounds__(256) void scan_pass3(int* __restrict__ offs,
                                                  const int* __restrict__ bsum,
                                                  int* __restrict__ cursor) {
    int i = blockIdx.x * 256 + threadIdx.x;
    if (i >= N_NODES) return;
    int o = offs[i] + bsum[blockIdx.x];
    offs[i] = o;
    cursor[i] = o;
}

__global__ __launch_bounds__(256) void csr_fill(const int* __restrict__ src,
                                                const int* __restrict__ dst,
                                                int* __restrict__ cursor,
                                                int* __restrict__ csr) {
    int e = blockIdx.x * blockDim.x + threadIdx.x;
    if (e >= N_EDGES) return;
    int pos = atomicAdd(cursor + dst[e], 1);
    csr[pos] = src[e];
}

// ---------------------------------------------------------------------------
// GIN aggregation (bf16): Hp[n] = (1+eps)*X[n] + sum X[nbr]; 8-deep pipelined.
// One node per 32 lanes (whole-row coalesced). Grid 2048.
// ---------------------------------------------------------------------------
__global__ __launch_bounds__(256) void gin_gather_bf(const ushort* __restrict__ Xbf,
                                                     ushort* __restrict__ Hp,
                                                     const int* __restrict__ offs,
                                                     const int* __restrict__ counts,
                                                     const int* __restrict__ csr,
                                                     const float* __restrict__ eps, int l) {
    int t = threadIdx.x;
    int tx = t & 31;
    int grp = t >> 5;
    int s0, s1;
    sub_range(blockIdx.x & 255, blockIdx.x >> 8, s0, s1);
    float ev = 1.0f + eps[l];
    for (int node = s0 + grp; node < s1; node += 8) {
        ushort4 sv = *(const ushort4*)(Xbf + (long)node * HID + 4 * tx);
        float a0 = bf2f(sv.x) * ev, a1 = bf2f(sv.y) * ev;
        float a2 = bf2f(sv.z) * ev, a3 = bf2f(sv.w) * ev;
        int o = offs[node];
        int d = counts[node];
        int k = 0;
        for (; k + 8 <= d; k += 8) {
            int si[8];
#pragma unroll
            for (int j = 0; j < 8; ++j) si[j] = csr[o + k + j];
            ushort4 v[8];
#pragma unroll
            for (int j = 0; j < 8; ++j)
                v[j] = *(const ushort4*)(Xbf + (long)si[j] * HID + 4 * tx);
#pragma unroll
            for (int j = 0; j < 8; ++j) {
                a0 += bf2f(v[j].x); a1 += bf2f(v[j].y);
                a2 += bf2f(v[j].z); a3 += bf2f(v[j].w);
            }
        }
        for (; k + 4 <= d; k += 4) {
            int si[4];
#pragma unroll
            for (int j = 0; j < 4; ++j) si[j] = csr[o + k + j];
#pragma unroll
            for (int j = 0; j < 4; ++j) {
                ushort4 v = *(const ushort4*)(Xbf + (long)si[j] * HID + 4 * tx);
                a0 += bf2f(v.x); a1 += bf2f(v.y); a2 += bf2f(v.z); a3 += bf2f(v.w);
            }
        }
        for (; k < d; ++k) {
            int s = csr[o + k];
            ushort4 v = *(const ushort4*)(Xbf + (long)s * HID + 4 * tx);
            a0 += bf2f(v.x); a1 += bf2f(v.y); a2 += bf2f(v.z); a3 += bf2f(v.w);
        }
        ushort4 w;
        w.x = f2bf(a0); w.y = f2bf(a1); w.z = f2bf(a2); w.w = f2bf(a3);
        *(ushort4*)(Hp + (long)node * HID + 4 * tx) = w;
    }
}

// ---------------------------------------------------------------------------
// Persistent MFMA GEMM, wave-pair column split, contiguous tiles (grid 512 ->
// 2 blocks/CU, 2 waves/SIMD), register B + next-tile prefetch, fused BN+gelu
// on A-load.
// ---------------------------------------------------------------------------
__global__ __launch_bounds__(256, 1) void gemm_persist(
    const ushort* __restrict__ Abf, const ushort* __restrict__ Wt,
    const float* __restrict__ bias, ushort* __restrict__ Cbf,
    const float* __restrict__ statsIn, const float* __restrict__ gIn,
    const float* __restrict__ bIn, int applyIn, float* __restrict__ statsOut) {
    __shared__ float scL[HID], sfL[HID];
    __shared__ __align__(16) ushort T[4][16 * TLD];
    __shared__ float shs[8 * 64];
    int t = threadIdx.x;
    if (applyIn && t < HID) {
        const float invN = 1.0f / (float)N_NODES;
        float mean = statsIn[t * SSTR] * invN;
        float var = statsIn[(HID + t) * SSTR] * invN - mean * mean;
        float s = gIn[t] * rsqrtf(var + 1e-5f);
        scL[t] = s;
        sfL[t] = bIn[t] - mean * s;
    }
    __syncthreads();

    int w = t >> 6, lane = t & 63;
    int m = lane & 15, q = lane >> 4;
    int c2 = w & 1, r2 = w >> 1;
    ushort* Tw = T[w];

    const ushort* Wh = Wt + (long)(c2 * 64) * HID;
    bf16x8 Bfrag[4][4];
#pragma unroll
    for (int nt = 0; nt < 4; ++nt)
#pragma unroll
        for (int kc = 0; kc < 4; ++kc)
            Bfrag[nt][kc] = *(const bf16x8*)(Wh + (nt * 16 + m) * HID + kc * 32 + q * 8);

    float bias4[4];
#pragma unroll
    for (int nt = 0; nt < 4; ++nt) bias4[nt] = bias[c2 * 64 + nt * 16 + m];

    float s_col[4], q_col[4];
#pragma unroll
    for (int nt = 0; nt < 4; ++nt) { s_col[nt] = 0.f; q_col[nt] = 0.f; }

    int t0 = (int)(((long)blockIdx.x * N_TILES) >> 9);        // grid 512
    int t1 = (int)(((long)(blockIdx.x + 1) * N_TILES) >> 9);

    int tile = t0 + r2;
    Chunk Ac[4];
    if (tile < t1) {
        const ushort* arow = Abf + (long)(tile * 16 + m) * HID + q * 8;
#pragma unroll
        for (int kc = 0; kc < 4; ++kc) Ac[kc].u4 = *(const uint4*)(arow + kc * 32);
    }
    while (tile < t1) {
        int nxt = tile + 2;
        Chunk An[4];
        if (nxt < t1) {
            const ushort* arow = Abf + (long)(nxt * 16 + m) * HID + q * 8;
#pragma unroll
            for (int kc = 0; kc < 4; ++kc) An[kc].u4 = *(const uint4*)(arow + kc * 32);
        }
        if (applyIn) {
#pragma unroll
            for (int kc = 0; kc < 4; ++kc)
#pragma unroll
                for (int j = 0; j < 8; ++j) {
                    int k = kc * 32 + q * 8 + j;
                    float f = bf2f(Ac[kc].us[j]) * scL[k] + sfL[k];
                    Ac[kc].us[j] = f2bf(gelu_fast(f));
                }
        }
        f32x4 acc[4];
#pragma unroll
        for (int nt = 0; nt < 4; ++nt) acc[nt] = (f32x4){0.f, 0.f, 0.f, 0.f};
#pragma unroll
        for (int kc = 0; kc < 4; ++kc)
#pragma unroll
            for (int nt = 0; nt < 4; ++nt)
                acc[nt] = __builtin_amdgcn_mfma_f32_16x16x32_bf16(Ac[kc].v, Bfrag[nt][kc],
                                                                  acc[nt], 0, 0, 0);
#pragma unroll
        for (int nt = 0; nt < 4; ++nt) {
            int col = nt * 16 + m;
#pragma unroll
            for (int r = 0; r < 4; ++r) {
                float z = acc[nt][r] + bias4[nt];
                Tw[(q * 4 + r) * TLD + col] = f2bf(z);
                s_col[nt] += z;
                q_col[nt] += z * z;
            }
        }
        long cbase = (long)(tile * 16) * HID + c2 * 64;
#pragma unroll
        for (int i = 0; i < 2; ++i) {
            int slot = i * 64 + lane;
            int row = slot >> 3, off = slot & 7;
            uint4 vv = *(const uint4*)(Tw + row * TLD + off * 8);
            *(uint4*)(Cbf + cbase + (long)row * HID + off * 8) = vv;
        }
        tile = nxt;
#pragma unroll
        for (int kc = 0; kc < 4; ++kc) Ac[kc] = An[kc];
    }

#pragma unroll
    for (int nt = 0; nt < 4; ++nt) {
        s_col[nt] += __shfl_xor(s_col[nt], 16);
        s_col[nt] += __shfl_xor(s_col[nt], 32);
        q_col[nt] += __shfl_xor(q_col[nt], 16);
        q_col[nt] += __shfl_xor(q_col[nt], 32);
    }
    if (q == 0) {
#pragma unroll
        for (int nt = 0; nt < 4; ++nt) {
            shs[w * 64 + nt * 16 + m] = s_col[nt];
            shs[256 + w * 64 + nt * 16 + m] = q_col[nt];
        }
    }
    __syncthreads();
    if (t < HID) {
        int half = t >> 6, lc = t & 63;
        float a = shs[half * 64 + lc] + shs[(2 + half) * 64 + lc];
        float b = shs[256 + half * 64 + lc] + shs[256 + (2 + half) * 64 + lc];
        atomicAdd(statsOut + t * SSTR, a);
        atomicAdd(statsOut + (HID + t) * SSTR, b);
    }
}

// ---------------------------------------------------------------------------
// Pool accumulator init: psum = 0, pmax = -inf
// ---------------------------------------------------------------------------
__global__ __launch_bounds__(256) void pool_init(float* __restrict__ psum,
                                                 float* __restrict__ pmax) {
    int i = blockIdx.x * 256 + threadIdx.x;
    if (i >= N_GRAPHS * HID) return;
    psum[i] = 0.f;
    pmax[i] = -INFINITY;
}

// ---------------------------------------------------------------------------
// FUSED JK attention + pooling accumulation. Grid 2048 x 4 waves = 8192 waves.
// ---------------------------------------------------------------------------
__global__ __launch_bounds__(256) void jk_pool(const ushort* __restrict__ H0,
                                               const ushort* __restrict__ H1,
                                               const ushort* __restrict__ H2,
                                               const ushort* __restrict__ H3,
                                               const float* __restrict__ att,
                                               const int* __restrict__ batch,
                                               float* __restrict__ psum,
                                               float* __restrict__ pmax) {
    int t = threadIdx.x;
    int lane = t & 63, w = t >> 6;
    long wid = (long)blockIdx.x * 4 + w;
    int a0 = (int)((wid * N_NODES) >> 13);
    int a1 = (int)(((wid + 1) * N_NODES) >> 13);
    const ushort* Hs[4] = {H0, H1, H2, H3};
    float2 av[4];
#pragma unroll
    for (int l = 0; l < 4; ++l) av[l] = *(const float2*)(att + l * HID + 2 * lane);

    int curg = -1;
    float sx = 0.f, sy = 0.f, mx = -INFINITY, my = -INFINITY;
    for (int node = a0; node < a1; ++node) {
        int g = batch[node];
        if (g != curg) {
            if (curg >= 0) {
                float* ps = psum + (long)curg * HID + 2 * lane;
                float* pm = pmax + (long)curg * HID + 2 * lane;
                atomicAdd(ps, sx);
                atomicAdd(ps + 1, sy);
                atomicMaxF(pm, mx);
                atomicMaxF(pm + 1, my);
            }
            curg = g;
            sx = 0.f; sy = 0.f; mx = -INFINITY; my = -INFINITY;
        }
        float hx[4], hy[4], scr[4];
#pragma unroll
        for (int l = 0; l < 4; ++l) {
            unsigned int u = *(const unsigned int*)(Hs[l] + (long)node * HID + 2 * lane);
            float vx = bf2f((ushort)(u & 0xFFFF));
            float vy = bf2f((ushort)(u >> 16));
            hx[l] = vx; hy[l] = vy;
            float p = vx * av[l].x + vy * av[l].y;
#pragma unroll
            for (int off = 32; off > 0; off >>= 1) p += __shfl_xor(p, off);
            scr[l] = p * (1.0f / HID);
        }
        float mm = fmaxf(fmaxf(scr[0], scr[1]), fmaxf(scr[2], scr[3]));
        float e[4], se = 0.f;
#pragma unroll
        for (int l = 0; l < 4; ++l) { e[l] = expf(scr[l] - mm); se += e[l]; }
        float inv = 1.0f / se;
        float ox = 0.f, oy = 0.f;
#pragma unroll
        for (int l = 0; l < 4; ++l) {
            float a = e[l] * inv;
            ox += a * hx[l];
            oy += a * hy[l];
        }
        sx += ox; sy += oy;
        mx = fmaxf(mx, ox); my = fmaxf(my, oy);
    }
    if (curg >= 0) {
        float* ps = psum + (long)curg * HID + 2 * lane;
        float* pm = pmax + (long)curg * HID + 2 * lane;
        atomicAdd(ps, sx);
        atomicAdd(ps + 1, sy);
        atomicMaxF(pm, mx);
        atomicMaxF(pm + 1, my);
    }
}

// pooled = sum*e0 + mean*e1 + max*e2 (softmax(pw)); guards for empty graphs.
__global__ __launch_bounds__(128) void pool_finalize(const float* __restrict__ psum,
                                                     const float* __restrict__ pmax,
                                                     const int* __restrict__ gstart,
                                                     const int* __restrict__ gend,
                                                     const float* __restrict__ pw,
                                                     float* __restrict__ pooled) {
    int g = blockIdx.x, f = threadIdx.x;
    float w0 = pw[0], w1 = pw[1], w2 = pw[2];
    float m = fmaxf(w0, fmaxf(w1, w2));
    float e0 = expf(w0 - m), e1 = expf(w1 - m), e2 = expf(w2 - m);
    float inv = 1.0f / (e0 + e1 + e2);
    e0 *= inv; e1 *= inv; e2 *= inv;
    int cnt = gend[g] - gstart[g];
    float s = psum[g * HID + f];
    float mx = pmax[g * HID + f];
    float mean = cnt > 0 ? s / (float)cnt : 0.f;
    float mxv = cnt > 0 ? mx : 0.f;
    pooled[g * HID + f] = s * e0 + mean * e1 + mxv * e2;
}

__global__ void graph_ranges(const int* __restrict__ batch, int* __restrict__ gstart,
                             int* __restrict__ gend) {
    int n = blockIdx.x * blockDim.x + threadIdx.x;
    if (n >= N_NODES) return;
    int b = batch[n];
    if (n == 0 || batch[n - 1] != b) gstart[b] = n;
    if (n == N_NODES - 1 || batch[n + 1] != b) gend[b] = n + 1;
}

__global__ __launch_bounds__(128) void head_kernel(const float* __restrict__ pooled,
                                                   const float* __restrict__ fcAw,
                                                   const float* __restrict__ fcAb,
                                                   const float* __restrict__ lng,
                                                   const float* __restrict__ lnb,
                                                   const float* __restrict__ fcBw,
                                                   const float* __restrict__ fcBb,
                                                   float* __restrict__ out) {
    __shared__ float p[HID], q[HID], red[HID];
    int g = blockIdx.x, j = threadIdx.x;
    p[j] = pooled[g * HID + j];
    __syncthreads();
    float acc = fcAb[j];
    for (int k = 0; k < HID; ++k) acc += p[k] * fcAw[k * HID + j];
    red[j] = acc;
    __syncthreads();
    for (int off = 64; off > 0; off >>= 1) {
        if (j < off) red[j] += red[j + off];
        __syncthreads();
    }
    float mean = red[0] * (1.0f / HID);
    __syncthreads();
    float d = acc - mean;
    red[j] = d * d;
    __syncthreads();
    for (int off = 64; off > 0; off >>= 1) {
        if (j < off) red[j] += red[j + off];
        __syncthreads();
    }
    float var = red[0] * (1.0f / HID);
    float y = d * rsqrtf(var + 1e-5f) * lng[j] + lnb[j];
    q[j] = gelu_exact(y) + p[j];
    __syncthreads();
    if (j < LAT) {
        float o = fcBb[j];
        for (int k = 0; k < HID; ++k) o += q[k] * fcBw[k * LAT + j];
        out[g * LAT + j] = o;
    }
}

extern "C" void kernel_launch(void* const* d_in, const int* in_sizes, int n_in,
                              void* d_out, int out_size, void* d_ws, size_t ws_size,
                              hipStream_t stream) {
    const float* x = (const float*)d_in[0];
    const int* ei = (const int*)d_in[1];
    const int* src = ei;
    const int* dst = ei + N_EDGES;
    const int* batch = (const int*)d_in[2];
    const float* ibn_g = (const float*)d_in[3];
    const float* ibn_b = (const float*)d_in[4];
    const float* eps = (const float*)d_in[5];
    const float* fc1w = (const float*)d_in[6];
    const float* fc1b = (const float*)d_in[7];
    const float* bn1g = (const float*)d_in[8];
    const float* bn1b = (const float*)d_in[9];
    const float* fc2w = (const float*)d_in[10];
    const float* fc2b = (const float*)d_in[11];
    const float* bng = (const float*)d_in[12];
    const float* bnb = (const float*)d_in[13];
    const float* att = (const float*)d_in[14];
    const float* pw = (const float*)d_in[15];
    const float* fcAw = (const float*)d_in[16];
    const float* fcAb = (const float*)d_in[17];
    const float* lng = (const float*)d_in[18];
    const float* lnb = (const float*)d_in[19];
    const float* fcBw = (const float*)d_in[20];
    const float* fcBb = (const float*)d_in[21];
    float* out = (float*)d_out;

    const size_t NH = (size_t)N_NODES * HID;
    char* w8 = (char*)d_ws;
    ushort* x0bf = (ushort*)w8;     w8 += NH * 2;
    ushort* hprebf = (ushort*)w8;   w8 += NH * 2;  // gather out / GEMM1 in
    ushort* z1bf = (ushort*)w8;     w8 += NH * 2;  // GEMM1 out / GEMM2 in
    ushort* z2bf = (ushort*)w8;     w8 += NH * 2;  // GEMM2 out (pre-final-BN)
    ushort* Hlbf[NL];
    for (int l = 0; l < NL; ++l) { Hlbf[l] = (ushort*)w8; w8 += NH * 2; }
    float* statsAll = (float*)w8;   w8 += (size_t)9 * SSET * 4;
    float* psum = (float*)w8;       w8 += (size_t)N_GRAPHS * HID * 4;
    float* pmax = (float*)w8;       w8 += (size_t)N_GRAPHS * HID * 4;
    float* pooled = (float*)w8;     w8 += (size_t)N_GRAPHS * HID * 4;
    int* gstart = (int*)w8;         w8 += N_GRAPHS * 4;
    int* gend = (int*)w8;           w8 += N_GRAPHS * 4;
    int* counts = (int*)w8;         w8 += N_NODES * 4;
    int* offs = (int*)w8;           w8 += N_NODES * 4;
    int* cursor = (int*)w8;         w8 += N_NODES * 4;
    int* bsum = (int*)w8;           w8 += 256 * 4;
    int* csr = (int*)w8;            w8 += (size_t)N_EDGES * 4;
    ushort* WtBf = (ushort*)w8;     w8 += (size_t)8 * HID * HID * 2;

    const int nodeBlocks = (N_NODES + 255) / 256;
    const int edgeBlocks = (N_EDGES + 255) / 256;

    // weights once
    wt_build<<<512, 256, 0, stream>>>(fc1w, fc2w, WtBf);

    // CSR build
    hipMemsetAsync(counts, 0, N_NODES * sizeof(int), stream);
    csr_count<<<edgeBlocks, 256, 0, stream>>>(dst, counts);
    scan_pass1<<<nodeBlocks, 256, 0, stream>>>(counts, offs, bsum);
    scan_pass2<<<1, 256, 0, stream>>>(bsum, nodeBlocks);
    scan_pass3<<<nodeBlocks, 256, 0, stream>>>(offs, bsum, cursor);
    csr_fill<<<edgeBlocks, 256, 0, stream>>>(src, dst, cursor, csr);

    // zero all padded stat sets once
    hipMemsetAsync(statsAll, 0, (size_t)9 * SSET * sizeof(float), stream);

    // input BN -> bf16 x0
    col_stats<<<256, 256, 0, stream>>>(x, statsAll);
    bn_apply_f32<<<2048, 256, 0, stream>>>(x, x0bf, statsAll, ibn_g, ibn_b);

    const ushort* xin = x0bf;
    for (int l = 0; l < NL; ++l) {
        float* st1 = statsAll + (size_t)(1 + 2 * l) * SSET;
        float* st2 = statsAll + (size_t)(2 + 2 * l) * SSET;
        gin_gather_bf<<<2048, 256, 0, stream>>>(xin, hprebf, offs, counts, csr, eps, l);
        gemm_persist<<<512, 256, 0, stream>>>(hprebf, WtBf + (size_t)l * HID * HID,
                                              fc1b + l * HID, z1bf,
                                              nullptr, nullptr, nullptr, 0, st1);
        gemm_persist<<<512, 256, 0, stream>>>(z1bf, WtBf + (size_t)(4 + l) * HID * HID,
                                              fc2b + l * HID, z2bf,
                                              st1, bn1g + l * HID, bn1b + l * HID, 1, st2);
        bn_apply_bf<<<2048, 256, 0, stream>>>(z2bf, Hlbf[l], st2, bng + l * HID,
                                              bnb + l * HID);
        xin = Hlbf[l];
    }

    // fused JK attention + pooling accumulation
    pool_init<<<(N_GRAPHS * HID + 255) / 256, 256, 0, stream>>>(psum, pmax);
    hipMemsetAsync(gstart, 0, 2 * N_GRAPHS * sizeof(int), stream);
    graph_ranges<<<nodeBlocks, 256, 0, stream>>>(batch, gstart, gend);
    jk_pool<<<2048, 256, 0, stream>>>(Hlbf[0], Hlbf[1], Hlbf[2], Hlbf[3], att, batch,
                                      psum, pmax);
    pool_finalize<<<N_GRAPHS, 128, 0, stream>>>(psum, pmax, gstart, gend, pw, pooled);

    // head
    head_kernel<<<N_GRAPHS, 128, 0, stream>>>(pooled, fcAw, fcAb, lng, lnb, fcBw, fcBb, out);
}

// Round 16
// 527.715 us; speedup vs baseline: 1.0872x; 1.0872x over previous
//
#include <hip/hip_runtime.h>
#include <math.h>

#define N_NODES 50000
#define N_EDGES 600000
#define N_GRAPHS 512
#define HID 128
#define LAT 64
#define NL 4
#define SSTR 16        // stats padding: 1 float per 64B cache line
#define SSET 4096      // floats per stat set: 256 entries * 16
#define N_TILES 3125   // 16-row tiles, exact
#define TLD 72         // per-wave LDS C half-tile row stride (ushort), 64+8 pad

typedef __attribute__((ext_vector_type(8))) __bf16 bf16x8;
typedef __attribute__((ext_vector_type(4))) float f32x4;

union Chunk {
    bf16x8 v;
    uint4 u4;
    ushort us[8];
};

__device__ __forceinline__ float gelu_exact(float x) {
    return 0.5f * x * (1.0f + erff(x * 0.70710678118654752f));
}
// Branchless gelu via A&S 7.1.26 erf poly (|err| <= 1.5e-7) + fast exp/rcp.
__device__ __forceinline__ float gelu_fast(float x) {
    float ax = fabsf(x) * 0.70710678118654752f;
    float t = __builtin_amdgcn_rcpf(fmaf(0.3275911f, ax, 1.0f));
    float p = t * (0.254829592f +
              t * (-0.284496736f +
              t * (1.421413741f +
              t * (-1.453152027f + t * 1.061405429f))));
    float e = __expf(-ax * ax);
    float erfv = 1.0f - p * e;
    float erfs = copysignf(erfv, x);
    return 0.5f * x * (1.0f + erfs);
}
__device__ __forceinline__ float bf2f(ushort h) {
    return __uint_as_float(((unsigned int)h) << 16);
}
__device__ __forceinline__ ushort f2bf(float f) {  // RNE
    unsigned int u = __float_as_uint(f);
    unsigned int r = (u + 0x7FFFu + ((u >> 16) & 1u)) >> 16;
    return (ushort)r;
}
// float atomic max via sign trick (init to -inf)
__device__ __forceinline__ void atomicMaxF(float* addr, float v) {
    if (v >= 0.f) atomicMax((int*)addr, __float_as_int(v));
    else atomicMin((unsigned int*)addr, __float_as_uint(v));
}

// Canonical row partition p (0..255) -> sub-chunk j (0..7) -> [s0, s1)
__device__ __forceinline__ void sub_range(int p, int j, int& s0, int& s1) {
    int r0 = (p * N_NODES) >> 8;
    int r1 = ((p + 1) * N_NODES) >> 8;
    int len = r1 - r0;
    s0 = r0 + ((len * j) >> 3);
    s1 = r0 + ((len * (j + 1)) >> 3);
}

// ---------------------------------------------------------------------------
// Weight pre-transpose + bf16: Wt[g][n][k] = W_g[k][n], g=0..3 fc1, 4..7 fc2
// ---------------------------------------------------------------------------
__global__ __launch_bounds__(256) void wt_build(const float* __restrict__ fc1w,
                                                const float* __restrict__ fc2w,
                                                ushort* __restrict__ Wt) {
    int i = blockIdx.x * 256 + threadIdx.x;  // 131072
    if (i >= 8 * HID * HID) return;
    int g = i >> 14;
    int rem = i & 16383;
    int n = rem >> 7, k = rem & 127;
    const float* W = (g < 4) ? (fc1w + (long)g * HID * HID) : (fc2w + (long)(g - 4) * HID * HID);
    Wt[i] = f2bf(W[k * HID + n]);
}

// ---------------------------------------------------------------------------
// Column stats over fp32 X -> padded stats
// ---------------------------------------------------------------------------
__global__ __launch_bounds__(256) void col_stats(const float* __restrict__ X,
                                                 float* __restrict__ stats) {
    __shared__ float sh[2048];
    int t = threadIdx.x;
    int tx = t & 31, ty = t >> 5;
    float s[4] = {0, 0, 0, 0}, q[4] = {0, 0, 0, 0};
    const int nTiles = (N_NODES + 63) / 64;  // 782
    for (int tile = blockIdx.x; tile < nTiles; tile += gridDim.x) {
        int r0 = tile * 64;
#pragma unroll
        for (int i = 0; i < 8; ++i) {
            int r = r0 + ty + 8 * i;
            int rc = min(r, N_NODES - 1);
            float4 v = *(const float4*)(X + (long)rc * HID + 4 * tx);
            float w = (r < N_NODES) ? 1.f : 0.f;
            float x0 = v.x * w, x1 = v.y * w, x2 = v.z * w, x3 = v.w * w;
            s[0] += x0; s[1] += x1; s[2] += x2; s[3] += x3;
            q[0] += x0 * v.x; q[1] += x1 * v.y; q[2] += x2 * v.z; q[3] += x3 * v.w;
        }
    }
#pragma unroll
    for (int c = 0; c < 4; ++c) {
        sh[ty * HID + 4 * tx + c] = s[c];
        sh[1024 + ty * HID + 4 * tx + c] = q[c];
    }
    __syncthreads();
    if (ty == 0) {
#pragma unroll
        for (int c = 0; c < 4; ++c) {
            float a = 0, b = 0;
#pragma unroll
            for (int j = 0; j < 8; ++j) {
                a += sh[j * HID + 4 * tx + c];
                b += sh[1024 + j * HID + 4 * tx + c];
            }
            atomicAdd(stats + (4 * tx + c) * SSTR, a);
            atomicAdd(stats + (HID + 4 * tx + c) * SSTR, b);
        }
    }
}

// ---------------------------------------------------------------------------
// BN apply, fp32 in -> bf16 out (input BN). Grid 2048.
// ---------------------------------------------------------------------------
__global__ __launch_bounds__(256) void bn_apply_f32(const float* __restrict__ X,
                                                    ushort* __restrict__ Y,
                                                    const float* __restrict__ stats,
                                                    const float* __restrict__ g,
                                                    const float* __restrict__ b) {
    __shared__ float scL[HID], sfL[HID];
    int t = threadIdx.x;
    if (t < HID) {
        const float invN = 1.0f / (float)N_NODES;
        float mean = stats[t * SSTR] * invN;
        float var = stats[(HID + t) * SSTR] * invN - mean * mean;
        float s = g[t] * rsqrtf(var + 1e-5f);
        scL[t] = s;
        sfL[t] = b[t] - mean * s;
    }
    __syncthreads();
    int c4 = (t & 31) * 4;
    float sc[4], sf[4];
#pragma unroll
    for (int j = 0; j < 4; ++j) { sc[j] = scL[c4 + j]; sf[j] = sfL[c4 + j]; }
    int s0, s1;
    sub_range(blockIdx.x & 255, blockIdx.x >> 8, s0, s1);
    int c0 = s0 * 32, c1 = s1 * 32;
    for (int i = c0 + t; i < c1; i += 256) {
        float4 v = ((const float4*)X)[i];
        ushort4 w;
        w.x = f2bf(v.x * sc[0] + sf[0]);
        w.y = f2bf(v.y * sc[1] + sf[1]);
        w.z = f2bf(v.z * sc[2] + sf[2]);
        w.w = f2bf(v.w * sc[3] + sf[3]);
        ((ushort4*)Y)[i] = w;
    }
}

// BN + gelu, bf16 in -> bf16 out. Grid 2048.
__global__ __launch_bounds__(256) void bn_apply_bf(const ushort* __restrict__ X,
                                                   ushort* __restrict__ Y,
                                                   const float* __restrict__ stats,
                                                   const float* __restrict__ g,
                                                   const float* __restrict__ b) {
    __shared__ float scL[HID], sfL[HID];
    int t = threadIdx.x;
    if (t < HID) {
        const float invN = 1.0f / (float)N_NODES;
        float mean = stats[t * SSTR] * invN;
        float var = stats[(HID + t) * SSTR] * invN - mean * mean;
        float s = g[t] * rsqrtf(var + 1e-5f);
        scL[t] = s;
        sfL[t] = b[t] - mean * s;
    }
    __syncthreads();
    int c8 = (t & 15) * 8;
    float sc[8], sf[8];
#pragma unroll
    for (int j = 0; j < 8; ++j) { sc[j] = scL[c8 + j]; sf[j] = sfL[c8 + j]; }
    int s0, s1;
    sub_range(blockIdx.x & 255, blockIdx.x >> 8, s0, s1);
    int c0 = s0 * 16, c1 = s1 * 16;
    for (int i = c0 + t; i < c1; i += 256) {
        Chunk ch;
        ch.u4 = ((const uint4*)X)[i];
#pragma unroll
        for (int j = 0; j < 8; ++j) {
            float f = bf2f(ch.us[j]) * sc[j] + sf[j];
            ch.us[j] = f2bf(gelu_fast(f));
        }
        ((uint4*)Y)[i] = ch.u4;
    }
}

// ---------------------------------------------------------------------------
// CSR build: counting sort of edges by dst
// ---------------------------------------------------------------------------
__global__ __launch_bounds__(256) void csr_count(const int* __restrict__ dst,
                                                 int* __restrict__ counts) {
    int e = blockIdx.x * blockDim.x + threadIdx.x;
    if (e >= N_EDGES) return;
    atomicAdd(counts + dst[e], 1);
}

__global__ __launch_bounds__(256) void scan_pass1(const int* __restrict__ counts,
                                                  int* __restrict__ offs,
                                                  int* __restrict__ bsum) {
    __shared__ int sh[256];
    int t = threadIdx.x;
    int i = blockIdx.x * 256 + t;
    int v = (i < N_NODES) ? counts[i] : 0;
    sh[t] = v;
    __syncthreads();
    for (int off = 1; off < 256; off <<= 1) {
        int a = (t >= off) ? sh[t - off] : 0;
        __syncthreads();
        sh[t] += a;
        __syncthreads();
    }
    if (i < N_NODES) offs[i] = sh[t] - v;
    if (t == 255) bsum[blockIdx.x] = sh[255];
}

__global__ __launch_bounds__(256) void scan_pass2(int* __restrict__ bsum, int nblk) {
    __shared__ int sh[256];
    int t = threadIdx.x;
    int v = (t < nblk) ? bsum[t] : 0;
    sh[t] = v;
    __syncthreads();
    for (int off = 1; off < 256; off <<= 1) {
        int a = (t >= off) ? sh[t - off] : 0;
        __syncthreads();
        sh[t] += a;
        __syncthreads();
    }
    if (t < nblk) bsum[t] = sh[t] - v;
}

__global__ __launch_bounds__(256) void scan_pass3(int* __restrict__ offs,
                                                  const int* __restrict__ bsum,
                                                  int* __restrict__ cursor) {
    int i = blockIdx.x * 256 + threadIdx.x;
    if (i >= N_NODES) return;
    int o = offs[i] + bsum[blockIdx.x];
    offs[i] = o;
    cursor[i] = o;
}

__global__ __launch_bounds__(256) void csr_fill(const int* __restrict__ src,
                                                const int* __restrict__ dst,
                                                int* __restrict__ cursor,
                                                int* __restrict__ csr) {
    int e = blockIdx.x * blockDim.x + threadIdx.x;
    if (e >= N_EDGES) return;
    int pos = atomicAdd(cursor + dst[e], 1);
    csr[pos] = src[e];
}

// ---------------------------------------------------------------------------
// GIN aggregation (bf16): Hp[n] = (1+eps)*X[n] + sum X[nbr]; 8-deep pipelined.
// One node per 32 lanes (whole-row coalesced). Grid 2048.
// ---------------------------------------------------------------------------
__global__ __launch_bounds__(256) void gin_gather_bf(const ushort* __restrict__ Xbf,
                                                     ushort* __restrict__ Hp,
                                                     const int* __restrict__ offs,
                                                     const int* __restrict__ counts,
                                                     const int* __restrict__ csr,
                                                     const float* __restrict__ eps, int l) {
    int t = threadIdx.x;
    int tx = t & 31;
    int grp = t >> 5;
    int s0, s1;
    sub_range(blockIdx.x & 255, blockIdx.x >> 8, s0, s1);
    float ev = 1.0f + eps[l];
    for (int node = s0 + grp; node < s1; node += 8) {
        ushort4 sv = *(const ushort4*)(Xbf + (long)node * HID + 4 * tx);
        float a0 = bf2f(sv.x) * ev, a1 = bf2f(sv.y) * ev;
        float a2 = bf2f(sv.z) * ev, a3 = bf2f(sv.w) * ev;
        int o = offs[node];
        int d = counts[node];
        int k = 0;
        for (; k + 8 <= d; k += 8) {
            int si[8];
#pragma unroll
            for (int j = 0; j < 8; ++j) si[j] = csr[o + k + j];
            ushort4 v[8];
#pragma unroll
            for (int j = 0; j < 8; ++j)
                v[j] = *(const ushort4*)(Xbf + (long)si[j] * HID + 4 * tx);
#pragma unroll
            for (int j = 0; j < 8; ++j) {
                a0 += bf2f(v[j].x); a1 += bf2f(v[j].y);
                a2 += bf2f(v[j].z); a3 += bf2f(v[j].w);
            }
        }
        for (; k + 4 <= d; k += 4) {
            int si[4];
#pragma unroll
            for (int j = 0; j < 4; ++j) si[j] = csr[o + k + j];
#pragma unroll
            for (int j = 0; j < 4; ++j) {
                ushort4 v = *(const ushort4*)(Xbf + (long)si[j] * HID + 4 * tx);
                a0 += bf2f(v.x); a1 += bf2f(v.y); a2 += bf2f(v.z); a3 += bf2f(v.w);
            }
        }
        for (; k < d; ++k) {
            int s = csr[o + k];
            ushort4 v = *(const ushort4*)(Xbf + (long)s * HID + 4 * tx);
            a0 += bf2f(v.x); a1 += bf2f(v.y); a2 += bf2f(v.z); a3 += bf2f(v.w);
        }
        ushort4 w;
        w.x = f2bf(a0); w.y = f2bf(a1); w.z = f2bf(a2); w.w = f2bf(a3);
        *(ushort4*)(Hp + (long)node * HID + 4 * tx) = w;
    }
}

// ---------------------------------------------------------------------------
// Persistent MFMA GEMM, wave-pair column split, contiguous tiles (grid 256 =
// 1 block/CU — matched to launch_bounds(256,1) register budget; grid 512
// regressed: blocks can't co-reside), register B + next-tile prefetch,
// fused BN+gelu on A-load.
// ---------------------------------------------------------------------------
__global__ __launch_bounds__(256, 1) void gemm_persist(
    const ushort* __restrict__ Abf, const ushort* __restrict__ Wt,
    const float* __restrict__ bias, ushort* __restrict__ Cbf,
    const float* __restrict__ statsIn, const float* __restrict__ gIn,
    const float* __restrict__ bIn, int applyIn, float* __restrict__ statsOut) {
    __shared__ float scL[HID], sfL[HID];
    __shared__ __align__(16) ushort T[4][16 * TLD];
    __shared__ float shs[8 * 64];
    int t = threadIdx.x;
    if (applyIn && t < HID) {
        const float invN = 1.0f / (float)N_NODES;
        float mean = statsIn[t * SSTR] * invN;
        float var = statsIn[(HID + t) * SSTR] * invN - mean * mean;
        float s = gIn[t] * rsqrtf(var + 1e-5f);
        scL[t] = s;
        sfL[t] = bIn[t] - mean * s;
    }
    __syncthreads();

    int w = t >> 6, lane = t & 63;
    int m = lane & 15, q = lane >> 4;
    int c2 = w & 1, r2 = w >> 1;
    ushort* Tw = T[w];

    const ushort* Wh = Wt + (long)(c2 * 64) * HID;
    bf16x8 Bfrag[4][4];
#pragma unroll
    for (int nt = 0; nt < 4; ++nt)
#pragma unroll
        for (int kc = 0; kc < 4; ++kc)
            Bfrag[nt][kc] = *(const bf16x8*)(Wh + (nt * 16 + m) * HID + kc * 32 + q * 8);

    float bias4[4];
#pragma unroll
    for (int nt = 0; nt < 4; ++nt) bias4[nt] = bias[c2 * 64 + nt * 16 + m];

    float s_col[4], q_col[4];
#pragma unroll
    for (int nt = 0; nt < 4; ++nt) { s_col[nt] = 0.f; q_col[nt] = 0.f; }

    int t0 = (blockIdx.x * N_TILES) >> 8;        // grid 256
    int t1 = ((blockIdx.x + 1) * N_TILES) >> 8;

    int tile = t0 + r2;
    Chunk Ac[4];
    if (tile < t1) {
        const ushort* arow = Abf + (long)(tile * 16 + m) * HID + q * 8;
#pragma unroll
        for (int kc = 0; kc < 4; ++kc) Ac[kc].u4 = *(const uint4*)(arow + kc * 32);
    }
    while (tile < t1) {
        int nxt = tile + 2;
        Chunk An[4];
        if (nxt < t1) {
            const ushort* arow = Abf + (long)(nxt * 16 + m) * HID + q * 8;
#pragma unroll
            for (int kc = 0; kc < 4; ++kc) An[kc].u4 = *(const uint4*)(arow + kc * 32);
        }
        if (applyIn) {
#pragma unroll
            for (int kc = 0; kc < 4; ++kc)
#pragma unroll
                for (int j = 0; j < 8; ++j) {
                    int k = kc * 32 + q * 8 + j;
                    float f = bf2f(Ac[kc].us[j]) * scL[k] + sfL[k];
                    Ac[kc].us[j] = f2bf(gelu_fast(f));
                }
        }
        f32x4 acc[4];
#pragma unroll
        for (int nt = 0; nt < 4; ++nt) acc[nt] = (f32x4){0.f, 0.f, 0.f, 0.f};
#pragma unroll
        for (int kc = 0; kc < 4; ++kc)
#pragma unroll
            for (int nt = 0; nt < 4; ++nt)
                acc[nt] = __builtin_amdgcn_mfma_f32_16x16x32_bf16(Ac[kc].v, Bfrag[nt][kc],
                                                                  acc[nt], 0, 0, 0);
#pragma unroll
        for (int nt = 0; nt < 4; ++nt) {
            int col = nt * 16 + m;
#pragma unroll
            for (int r = 0; r < 4; ++r) {
                float z = acc[nt][r] + bias4[nt];
                Tw[(q * 4 + r) * TLD + col] = f2bf(z);
                s_col[nt] += z;
                q_col[nt] += z * z;
            }
        }
        long cbase = (long)(tile * 16) * HID + c2 * 64;
#pragma unroll
        for (int i = 0; i < 2; ++i) {
            int slot = i * 64 + lane;
            int row = slot >> 3, off = slot & 7;
            uint4 vv = *(const uint4*)(Tw + row * TLD + off * 8);
            *(uint4*)(Cbf + cbase + (long)row * HID + off * 8) = vv;
        }
        tile = nxt;
#pragma unroll
        for (int kc = 0; kc < 4; ++kc) Ac[kc] = An[kc];
    }

#pragma unroll
    for (int nt = 0; nt < 4; ++nt) {
        s_col[nt] += __shfl_xor(s_col[nt], 16);
        s_col[nt] += __shfl_xor(s_col[nt], 32);
        q_col[nt] += __shfl_xor(q_col[nt], 16);
        q_col[nt] += __shfl_xor(q_col[nt], 32);
    }
    if (q == 0) {
#pragma unroll
        for (int nt = 0; nt < 4; ++nt) {
            shs[w * 64 + nt * 16 + m] = s_col[nt];
            shs[256 + w * 64 + nt * 16 + m] = q_col[nt];
        }
    }
    __syncthreads();
    if (t < HID) {
        int half = t >> 6, lc = t & 63;
        float a = shs[half * 64 + lc] + shs[(2 + half) * 64 + lc];
        float b = shs[256 + half * 64 + lc] + shs[256 + (2 + half) * 64 + lc];
        atomicAdd(statsOut + t * SSTR, a);
        atomicAdd(statsOut + (HID + t) * SSTR, b);
    }
}

// ---------------------------------------------------------------------------
// Pool accumulator init: psum = 0, pmax = -inf; also zeroes gstart/gend.
// ---------------------------------------------------------------------------
__global__ __launch_bounds__(256) void pool_init(float* __restrict__ psum,
                                                 float* __restrict__ pmax,
                                                 int* __restrict__ gstart,
                                                 int* __restrict__ gend) {
    int i = blockIdx.x * 256 + threadIdx.x;
    if (i < N_GRAPHS) { gstart[i] = 0; gend[i] = 0; }
    if (i >= N_GRAPHS * HID) return;
    psum[i] = 0.f;
    pmax[i] = -INFINITY;
}

// ---------------------------------------------------------------------------
// FUSED JK attention + pooling accumulation. Grid 2048 x 4 waves = 8192 waves.
// ---------------------------------------------------------------------------
__global__ __launch_bounds__(256) void jk_pool(const ushort* __restrict__ H0,
                                               const ushort* __restrict__ H1,
                                               const ushort* __restrict__ H2,
                                               const ushort* __restrict__ H3,
                                               const float* __restrict__ att,
                                               const int* __restrict__ batch,
                                               float* __restrict__ psum,
                                               float* __restrict__ pmax) {
    int t = threadIdx.x;
    int lane = t & 63, w = t >> 6;
    long wid = (long)blockIdx.x * 4 + w;
    int a0 = (int)((wid * N_NODES) >> 13);
    int a1 = (int)(((wid + 1) * N_NODES) >> 13);
    const ushort* Hs[4] = {H0, H1, H2, H3};
    float2 av[4];
#pragma unroll
    for (int l = 0; l < 4; ++l) av[l] = *(const float2*)(att + l * HID + 2 * lane);

    int curg = -1;
    float sx = 0.f, sy = 0.f, mx = -INFINITY, my = -INFINITY;
    for (int node = a0; node < a1; ++node) {
        int g = batch[node];
        if (g != curg) {
            if (curg >= 0) {
                float* ps = psum + (long)curg * HID + 2 * lane;
                float* pm = pmax + (long)curg * HID + 2 * lane;
                atomicAdd(ps, sx);
                atomicAdd(ps + 1, sy);
                atomicMaxF(pm, mx);
                atomicMaxF(pm + 1, my);
            }
            curg = g;
            sx = 0.f; sy = 0.f; mx = -INFINITY; my = -INFINITY;
        }
        float hx[4], hy[4], scr[4];
#pragma unroll
        for (int l = 0; l < 4; ++l) {
            unsigned int u = *(const unsigned int*)(Hs[l] + (long)node * HID + 2 * lane);
            float vx = bf2f((ushort)(u & 0xFFFF));
            float vy = bf2f((ushort)(u >> 16));
            hx[l] = vx; hy[l] = vy;
            float p = vx * av[l].x + vy * av[l].y;
#pragma unroll
            for (int off = 32; off > 0; off >>= 1) p += __shfl_xor(p, off);
            scr[l] = p * (1.0f / HID);
        }
        float mm = fmaxf(fmaxf(scr[0], scr[1]), fmaxf(scr[2], scr[3]));
        float e[4], se = 0.f;
#pragma unroll
        for (int l = 0; l < 4; ++l) { e[l] = expf(scr[l] - mm); se += e[l]; }
        float inv = 1.0f / se;
        float ox = 0.f, oy = 0.f;
#pragma unroll
        for (int l = 0; l < 4; ++l) {
            float a = e[l] * inv;
            ox += a * hx[l];
            oy += a * hy[l];
        }
        sx += ox; sy += oy;
        mx = fmaxf(mx, ox); my = fmaxf(my, oy);
    }
    if (curg >= 0) {
        float* ps = psum + (long)curg * HID + 2 * lane;
        float* pm = pmax + (long)curg * HID + 2 * lane;
        atomicAdd(ps, sx);
        atomicAdd(ps + 1, sy);
        atomicMaxF(pm, mx);
        atomicMaxF(pm + 1, my);
    }
}

// pooled = sum*e0 + mean*e1 + max*e2 (softmax(pw)); guards for empty graphs.
__global__ __launch_bounds__(128) void pool_finalize(const float* __restrict__ psum,
                                                     const float* __restrict__ pmax,
                                                     const int* __restrict__ gstart,
                                                     const int* __restrict__ gend,
                                                     const float* __restrict__ pw,
                                                     float* __restrict__ pooled) {
    int g = blockIdx.x, f = threadIdx.x;
    float w0 = pw[0], w1 = pw[1], w2 = pw[2];
    float m = fmaxf(w0, fmaxf(w1, w2));
    float e0 = expf(w0 - m), e1 = expf(w1 - m), e2 = expf(w2 - m);
    float inv = 1.0f / (e0 + e1 + e2);
    e0 *= inv; e1 *= inv; e2 *= inv;
    int cnt = gend[g] - gstart[g];
    float s = psum[g * HID + f];
    float mx = pmax[g * HID + f];
    float mean = cnt > 0 ? s / (float)cnt : 0.f;
    float mxv = cnt > 0 ? mx : 0.f;
    pooled[g * HID + f] = s * e0 + mean * e1 + mxv * e2;
}

__global__ void graph_ranges(const int* __restrict__ batch, int* __restrict__ gstart,
                             int* __restrict__ gend) {
    int n = blockIdx.x * blockDim.x + threadIdx.x;
    if (n >= N_NODES) return;
    int b = batch[n];
    if (n == 0 || batch[n - 1] != b) gstart[b] = n;
    if (n == N_NODES - 1 || batch[n + 1] != b) gend[b] = n + 1;
}

__global__ __launch_bounds__(128) void head_kernel(const float* __restrict__ pooled,
                                                   const float* __restrict__ fcAw,
                                                   const float* __restrict__ fcAb,
                                                   const float* __restrict__ lng,
                                                   const float* __restrict__ lnb,
                                                   const float* __restrict__ fcBw,
                                                   const float* __restrict__ fcBb,
                                                   float* __restrict__ out) {
    __shared__ float p[HID], q[HID], red[HID];
    int g = blockIdx.x, j = threadIdx.x;
    p[j] = pooled[g * HID + j];
    __syncthreads();
    float acc = fcAb[j];
    for (int k = 0; k < HID; ++k) acc += p[k] * fcAw[k * HID + j];
    red[j] = acc;
    __syncthreads();
    for (int off = 64; off > 0; off >>= 1) {
        if (j < off) red[j] += red[j + off];
        __syncthreads();
    }
    float mean = red[0] * (1.0f / HID);
    __syncthreads();
    float d = acc - mean;
    red[j] = d * d;
    __syncthreads();
    for (int off = 64; off > 0; off >>= 1) {
        if (j < off) red[j] += red[j + off];
        __syncthreads();
    }
    float var = red[0] * (1.0f / HID);
    float y = d * rsqrtf(var + 1e-5f) * lng[j] + lnb[j];
    q[j] = gelu_exact(y) + p[j];
    __syncthreads();
    if (j < LAT) {
        float o = fcBb[j];
        for (int k = 0; k < HID; ++k) o += q[k] * fcBw[k * LAT + j];
        out[g * LAT + j] = o;
    }
}

extern "C" void kernel_launch(void* const* d_in, const int* in_sizes, int n_in,
                              void* d_out, int out_size, void* d_ws, size_t ws_size,
                              hipStream_t stream) {
    const float* x = (const float*)d_in[0];
    const int* ei = (const int*)d_in[1];
    const int* src = ei;
    const int* dst = ei + N_EDGES;
    const int* batch = (const int*)d_in[2];
    const float* ibn_g = (const float*)d_in[3];
    const float* ibn_b = (const float*)d_in[4];
    const float* eps = (const float*)d_in[5];
    const float* fc1w = (const float*)d_in[6];
    const float* fc1b = (const float*)d_in[7];
    const float* bn1g = (const float*)d_in[8];
    const float* bn1b = (const float*)d_in[9];
    const float* fc2w = (const float*)d_in[10];
    const float* fc2b = (const float*)d_in[11];
    const float* bng = (const float*)d_in[12];
    const float* bnb = (const float*)d_in[13];
    const float* att = (const float*)d_in[14];
    const float* pw = (const float*)d_in[15];
    const float* fcAw = (const float*)d_in[16];
    const float* fcAb = (const float*)d_in[17];
    const float* lng = (const float*)d_in[18];
    const float* lnb = (const float*)d_in[19];
    const float* fcBw = (const float*)d_in[20];
    const float* fcBb = (const float*)d_in[21];
    float* out = (float*)d_out;

    const size_t NH = (size_t)N_NODES * HID;
    char* w8 = (char*)d_ws;
    ushort* x0bf = (ushort*)w8;     w8 += NH * 2;
    ushort* hprebf = (ushort*)w8;   w8 += NH * 2;  // gather out / GEMM1 in
    ushort* z1bf = (ushort*)w8;     w8 += NH * 2;  // GEMM1 out / GEMM2 in
    ushort* z2bf = (ushort*)w8;     w8 += NH * 2;  // GEMM2 out (pre-final-BN)
    ushort* Hlbf[NL];
    for (int l = 0; l < NL; ++l) { Hlbf[l] = (ushort*)w8; w8 += NH * 2; }
    float* statsAll = (float*)w8;   w8 += (size_t)9 * SSET * 4;
    float* psum = (float*)w8;       w8 += (size_t)N_GRAPHS * HID * 4;
    float* pmax = (float*)w8;       w8 += (size_t)N_GRAPHS * HID * 4;
    float* pooled = (float*)w8;     w8 += (size_t)N_GRAPHS * HID * 4;
    int* gstart = (int*)w8;         w8 += N_GRAPHS * 4;
    int* gend = (int*)w8;           w8 += N_GRAPHS * 4;
    int* counts = (int*)w8;         w8 += N_NODES * 4;
    int* offs = (int*)w8;           w8 += N_NODES * 4;
    int* cursor = (int*)w8;         w8 += N_NODES * 4;
    int* bsum = (int*)w8;           w8 += 256 * 4;
    int* csr = (int*)w8;            w8 += (size_t)N_EDGES * 4;
    ushort* WtBf = (ushort*)w8;     w8 += (size_t)8 * HID * HID * 2;

    const int nodeBlocks = (N_NODES + 255) / 256;
    const int edgeBlocks = (N_EDGES + 255) / 256;

    // weights once
    wt_build<<<512, 256, 0, stream>>>(fc1w, fc2w, WtBf);

    // CSR build + early pool/range init (independent of layer pipeline)
    hipMemsetAsync(counts, 0, N_NODES * sizeof(int), stream);
    csr_count<<<edgeBlocks, 256, 0, stream>>>(dst, counts);
    scan_pass1<<<nodeBlocks, 256, 0, stream>>>(counts, offs, bsum);
    scan_pass2<<<1, 256, 0, stream>>>(bsum, nodeBlocks);
    scan_pass3<<<nodeBlocks, 256, 0, stream>>>(offs, bsum, cursor);
    csr_fill<<<edgeBlocks, 256, 0, stream>>>(src, dst, cursor, csr);
    pool_init<<<(N_GRAPHS * HID + 255) / 256, 256, 0, stream>>>(psum, pmax, gstart, gend);
    graph_ranges<<<nodeBlocks, 256, 0, stream>>>(batch, gstart, gend);

    // zero all padded stat sets once
    hipMemsetAsync(statsAll, 0, (size_t)9 * SSET * sizeof(float), stream);

    // input BN -> bf16 x0
    col_stats<<<256, 256, 0, stream>>>(x, statsAll);
    bn_apply_f32<<<2048, 256, 0, stream>>>(x, x0bf, statsAll, ibn_g, ibn_b);

    const ushort* xin = x0bf;
    for (int l = 0; l < NL; ++l) {
        float* st1 = statsAll + (size_t)(1 + 2 * l) * SSET;
        float* st2 = statsAll + (size_t)(2 + 2 * l) * SSET;
        gin_gather_bf<<<2048, 256, 0, stream>>>(xin, hprebf, offs, counts, csr, eps, l);
        gemm_persist<<<256, 256, 0, stream>>>(hprebf, WtBf + (size_t)l * HID * HID,
                                              fc1b + l * HID, z1bf,
                                              nullptr, nullptr, nullptr, 0, st1);
        gemm_persist<<<256, 256, 0, stream>>>(z1bf, WtBf + (size_t)(4 + l) * HID * HID,
                                              fc2b + l * HID, z2bf,
                                              st1, bn1g + l * HID, bn1b + l * HID, 1, st2);
        bn_apply_bf<<<2048, 256, 0, stream>>>(z2bf, Hlbf[l], st2, bng + l * HID,
                                              bnb + l * HID);
        xin = Hlbf[l];
    }

    // fused JK attention + pooling accumulation
    jk_pool<<<2048, 256, 0, stream>>>(Hlbf[0], Hlbf[1], Hlbf[2], Hlbf[3], att, batch,
                                      psum, pmax);
    pool_finalize<<<N_GRAPHS, 128, 0, stream>>>(psum, pmax, gstart, gend, pw, pooled);

    // head
    head_kernel<<<N_GRAPHS, 128, 0, stream>>>(pooled, fcAw, fcAb, lng, lnb, fcBw, fcBb, out);
}